// Round 9
// baseline (356.585 us; speedup 1.0000x reference)
//
#include <hip/hip_runtime.h>
#include <hip/hip_fp16.h>

#define N_NODES 100000
#define N_EDGES 1600000
#define N_GRAPHS 512
#define F_IN 20
#define HID 128
#define OUT_F 64

#define BUCKETS 512
#define SPAN 196        // ceil(N_NODES / BUCKETS)
#define BCAP 3500       // per-bucket capacity (mean 3125, +6.7 sigma)
#define EPB 4096        // edges per partition block (512 threads x 8)

typedef _Float16 half8_t __attribute__((ext_vector_type(8)));
typedef float f32x4_t __attribute__((ext_vector_type(4)));
typedef unsigned int uv4 __attribute__((ext_vector_type(4)));

__device__ inline float4 h4_to_f4(uint2 u) {
    __half2 h0 = *(__half2*)&u.x;
    __half2 h1 = *(__half2*)&u.y;
    float2 f0 = __half22float2(h0);
    float2 f1 = __half22float2(h1);
    return make_float4(f0.x, f0.y, f1.x, f1.y);
}

__device__ inline float4 f4_from(unsigned a, unsigned b) {
    __half2 h0 = *(__half2*)&a;
    __half2 h1 = *(__half2*)&b;
    float2 f0 = __half22float2(h0);
    float2 f1 = __half22float2(h1);
    return make_float4(f0.x, f0.y, f1.x, f1.y);
}

__device__ inline void acc8(float4& aL, float4& aH, uv4 v) {
    float4 l_ = f4_from(v[0], v[1]);
    float4 h_ = f4_from(v[2], v[3]);
    aL.x += l_.x; aL.y += l_.y; aL.z += l_.z; aL.w += l_.w;
    aH.x += h_.x; aH.y += h_.y; aH.z += h_.z; aH.w += h_.w;
}

// ---------------- partition: block-sorted LDS staging -> coalesced bucket writes ----------------
__global__ __launch_bounds__(512) void partition(const int* __restrict__ src,
                                                 const int* __restrict__ dst,
                                                 int* __restrict__ bpairs,
                                                 int* cur512) {
    __shared__ int lcnt[8][BUCKETS];          // 16 KB  per-wave counts
    __shared__ int woff[8][BUCKETS];          // 16 KB  per-wave local (block) offsets
    __shared__ int loffx[BUCKETS];            // 2 KB   block exclusive offsets per bucket
    __shared__ int gbase[BUCKETS];            // 2 KB   global reserved base per bucket
    __shared__ int sc[512];                   // 2 KB   scan temp
    __shared__ int stage[EPB];                // 16 KB  staged pairs (bucket-sorted)
    __shared__ unsigned short sbuck[EPB];     // 8 KB   bucket id per staged slot
    __shared__ int stot;
    int t = threadIdx.x;
    int wv = t >> 6;
    for (int i = t; i < 8 * BUCKETS; i += 512) ((int*)lcnt)[i] = 0;
    __syncthreads();
    int base = blockIdx.x * EPB;
    int myb[8], myp[8], myr[8];
#pragma unroll
    for (int i = 0; i < 8; ++i) {
        int e = base + i * 512 + t;
        int b = -1, p = 0, rk = 0;
        if (e < N_EDGES) {
            int s = src[e], d = dst[e];
            b = d / SPAN;
            p = (s << 9) | (d - b * SPAN);
            rk = atomicAdd(&lcnt[wv][b], 1);
        }
        myb[i] = b; myp[i] = p; myr[i] = rk;
    }
    __syncthreads();
    // block totals per bucket + exclusive scan over buckets
    int c[8], tot = 0;
#pragma unroll
    for (int w = 0; w < 8; ++w) { c[w] = lcnt[w][t]; tot += c[w]; }
    sc[t] = tot;
    __syncthreads();
    for (int o = 1; o < BUCKETS; o <<= 1) {
        int v = (t >= o) ? sc[t - o] : 0;
        __syncthreads();
        sc[t] += v;
        __syncthreads();
    }
    int excl = sc[t] - tot;
    loffx[t] = excl;
    gbase[t] = atomicAdd(&cur512[t], tot);    // contiguous global run for this block+bucket
    {
        int lb = excl;
#pragma unroll
        for (int w = 0; w < 8; ++w) { woff[w][t] = lb; lb += c[w]; }
    }
    if (t == 511) stot = sc[511];
    __syncthreads();
    // stage into LDS, bucket-sorted
#pragma unroll
    for (int i = 0; i < 8; ++i) {
        int b = myb[i];
        if (b >= 0) {
            int slot = woff[wv][b] + myr[i];
            stage[slot] = myp[i];
            sbuck[slot] = (unsigned short)b;
        }
    }
    __syncthreads();
    // flush: consecutive staged slots of one bucket -> consecutive global addresses
    int n = stot;
    for (int i = t; i < n; i += 512) {
        int b = sbuck[i];
        int pos = gbase[b] + (i - loffx[b]);
        if (pos < BCAP) bpairs[(size_t)b * BCAP + pos] = stage[i];
    }
}

// ---------------- per-bucket CSR build, 512 thr (LDS-staged csr flush + scale_x) ----------------
__global__ __launch_bounds__(512) void csr_build(const int* __restrict__ bpairs,
                                                 const int* __restrict__ cur512,
                                                 int* __restrict__ row_st,
                                                 int* __restrict__ csr,
                                                 const float* __restrict__ x,
                                                 __half* __restrict__ Xs) {
    __shared__ int ocnt[SPAN];
    __shared__ int sc[512];
    __shared__ int cur[SPAN];
    __shared__ int lcsr[BCAP];    // 14 KB: stage csr segment, flush coalesced
    __shared__ int sbase;
    int b = blockIdx.x, t = threadIdx.x;

    // bucket base: exclusive scan of all 512 bucket counts
    int myc = cur512[t];
    sc[t] = myc;
    __syncthreads();
    for (int o = 1; o < BUCKETS; o <<= 1) {
        int v = (t >= o) ? sc[t - o] : 0;
        __syncthreads();
        sc[t] += v;
        __syncthreads();
    }
    if (t == b) sbase = sc[t] - myc;
    if (b == BUCKETS - 1 && t == 0) row_st[N_NODES] = N_EDGES;

    int n0 = b * SPAN;
    int span = N_NODES - n0; if (span > SPAN) span = SPAN;
    if (span < 0) span = 0;
    if (t < SPAN) ocnt[t] = 0;
    __syncthreads();

    int n = cur512[b];
    if (n > BCAP) n = BCAP;
    const int* p = bpairs + (size_t)b * BCAP;
    for (int i = t; i < n; i += 512) atomicAdd(&ocnt[p[i] & 511], 1);
    __syncthreads();
    sc[t] = (t < span) ? ocnt[t] : 0;
    __syncthreads();
    for (int o = 1; o < 512; o <<= 1) {
        int v = (t >= o) ? sc[t - o] : 0;
        __syncthreads();
        sc[t] += v;
        __syncthreads();
    }
    int base = sbase;
    if (t < span) {
        int start = sc[t] - ocnt[t];
        row_st[n0 + t] = base + start;
        cur[t] = start;
    }
    __syncthreads();
    for (int i = t; i < n; i += 512) {
        int e = p[i];
        int lp = atomicAdd(&cur[e & 511], 1);
        lcsr[lp] = e >> 9;                      // LDS scatter (cheap)
    }
    __syncthreads();
    for (int i = t; i < n; i += 512)            // coalesced global flush
        csr[base + i] = lcsr[i];
    // fused scale_x for this bucket's nodes
    for (int i = t; i < span * 32; i += 512) {
        int nl = i >> 5, f = i & 31;
        float v = (f < F_IN) ? x[(size_t)(n0 + nl) * F_IN + f] : 0.f;
        float di = rsqrtf((float)(ocnt[nl] + 1));
        Xs[(size_t)(n0 + nl) * 32 + f] = __float2half(di * v);
    }
}

// ---------------- layer-1 gather: barrier-free, wall-to-wall (4 lanes/node) ----------------
// A20[n][32] f32 = d_n * (Xs[n] + sum_{s in N(n)} Xs[s]).
__global__ __launch_bounds__(256) void gather20(const __half* __restrict__ Xs,
                                                const int* __restrict__ row_st,
                                                const int* __restrict__ csr,
                                                float* __restrict__ A20) {
    const int t = threadIdx.x;
    const int n = blockIdx.x * 64 + (t >> 2);
    const int l = t & 3;           // uint4 (8 halfs) within 64-B row
    if (n >= N_NODES) return;
    int r0 = row_st[n], r1 = row_st[n + 1];
    const uv4* X4 = (const uv4*)Xs;
    uv4 u = X4[(size_t)n * 4 + l];
    float4 accL = f4_from(u[0], u[1]);   // self term (Xs pre-scaled src-side)
    float4 accH = f4_from(u[2], u[3]);
    int r = r0;
    for (; r + 7 < r1; r += 8) {
        int s0 = csr[r],     s1 = csr[r + 1], s2 = csr[r + 2], s3 = csr[r + 3];
        int s4 = csr[r + 4], s5 = csr[r + 5], s6 = csr[r + 6], s7 = csr[r + 7];
        uv4 vv0 = X4[(size_t)s0 * 4 + l];
        uv4 vv1 = X4[(size_t)s1 * 4 + l];
        uv4 vv2 = X4[(size_t)s2 * 4 + l];
        uv4 vv3 = X4[(size_t)s3 * 4 + l];
        uv4 vv4 = X4[(size_t)s4 * 4 + l];
        uv4 vv5 = X4[(size_t)s5 * 4 + l];
        uv4 vv6 = X4[(size_t)s6 * 4 + l];
        uv4 vv7 = X4[(size_t)s7 * 4 + l];
        uv4 vv[8] = {vv0, vv1, vv2, vv3, vv4, vv5, vv6, vv7};
#pragma unroll
        for (int j = 0; j < 8; ++j) acc8(accL, accH, vv[j]);
    }
    for (; r < r1; ++r) acc8(accL, accH, X4[(size_t)csr[r] * 4 + l]);
    float di = rsqrtf((float)(r1 - r0 + 1));
    accL.x *= di; accL.y *= di; accL.z *= di; accL.w *= di;
    accH.x *= di; accH.y *= di; accH.z *= di; accH.w *= di;
    float4* ap = (float4*)(A20 + (size_t)n * 32 + l * 8);
    ap[0] = accL;
    ap[1] = accH;
}

// ---------------- fused layer-1 GEMM + layer-2 MFMA: A20 -> T, H never hits global ----------------
// Per 16-row strip (one wave each): H = A20(16x20) @ W1 + b1 in f32, relu -> fp16 into a
// per-wave XOR-swizzled LDS strip, then the proven MFMA x W2 (hi/lo split) -> T.
// Saves the 25.6 MB H write + 25.6 MB read and one dispatch vs gemm20 + gemm_mfma.
__global__ __launch_bounds__(256) void gemm_l1(const float* __restrict__ A20,
                                               const float* __restrict__ W1,
                                               const float* __restrict__ b1,
                                               const float* __restrict__ W2,
                                               const int* __restrict__ row_st,
                                               __half* __restrict__ T) {
    __shared__ _Float16 Whi[64 * 128];   // 16 KB
    __shared__ _Float16 Wlo[64 * 128];   // 16 KB
    __shared__ float W1s[F_IN * HID];    // 10 KB
    __shared__ __align__(16) _Float16 Hs[4][16 * 128];  // 16 KB (4 KB per wave)
    const int t = threadIdx.x;
    const int c0 = (blockIdx.x & 1) * 64;

    for (int i = t; i < 128 * 64; i += 256) {
        int k = i >> 6, c = i & 63;
        float w = W2[k * HID + c0 + c];
        _Float16 hi = (_Float16)w;
        _Float16 lo = (_Float16)((w - (float)hi) * 2048.0f);
        int addr = c * 128 + (((k >> 3) ^ (c & 15)) << 3) + (k & 7);
        Whi[addr] = hi;
        Wlo[addr] = lo;
    }
    for (int i = t; i < F_IN * HID; i += 256) W1s[i] = W1[i];
    __syncthreads();

    const int wv = t >> 6;
    const int ln = t & 63;
    const int lr = ln & 15;
    const int lq = ln >> 4;
    char* myrow = (char*)&Hs[wv][0] + lr * 256;     // this lane's H-strip row
    const int sw = (lr & 7) << 4;                   // XOR swizzle (round-4 proven)

    for (int rep = 0; rep < 4; ++rep) {
        int strip = ((blockIdx.x >> 1) * 4 + wv) * 4 + rep;
        if (strip >= N_NODES / 16) continue;
        int n0 = strip * 16;

        // ---- f32 GEMM phase: row lr, cols lq*32..lq*32+31 ----
        {
            float a[F_IN];
            const float* ar = A20 + (size_t)(n0 + lr) * 32;
#pragma unroll
            for (int k = 0; k < F_IN; ++k) a[k] = ar[k];
            const int cb = lq * 32;
#pragma unroll
            for (int q = 0; q < 4; ++q) {
                float v[8];
#pragma unroll
                for (int j = 0; j < 8; ++j) v[j] = b1[cb + q * 8 + j];
#pragma unroll
                for (int k = 0; k < F_IN; ++k) {
                    float av = a[k];
                    const float* wr = &W1s[k * HID + cb + q * 8];
#pragma unroll
                    for (int j = 0; j < 8; ++j) v[j] = fmaf(av, wr[j], v[j]);
                }
                __half2 h0 = __floats2half2_rn(fmaxf(v[0], 0.f), fmaxf(v[1], 0.f));
                __half2 h1 = __floats2half2_rn(fmaxf(v[2], 0.f), fmaxf(v[3], 0.f));
                __half2 h2 = __floats2half2_rn(fmaxf(v[4], 0.f), fmaxf(v[5], 0.f));
                __half2 h3 = __floats2half2_rn(fmaxf(v[6], 0.f), fmaxf(v[7], 0.f));
                uv4 u;
                u[0] = *(unsigned*)&h0; u[1] = *(unsigned*)&h1;
                u[2] = *(unsigned*)&h2; u[3] = *(unsigned*)&h3;
                *(uv4*)(myrow + ((lq * 64 + q * 16) ^ sw)) = u;
            }
        }
        // wave-private LDS strip: same-wave write->read; fence against compiler reorder
        asm volatile("s_waitcnt lgkmcnt(0)" ::: "memory");

        // ---- MFMA phase (relu already applied in fp16 conversion) ----
        f32x4_t acc[4], acl[4];
#pragma unroll
        for (int ct = 0; ct < 4; ++ct) { acc[ct] = (f32x4_t){0,0,0,0}; acl[ct] = (f32x4_t){0,0,0,0}; }
#pragma unroll
        for (int kc = 0; kc < 4; ++kc) {
            half8_t a = *(const half8_t*)(myrow + ((kc * 64 + lq * 16) ^ sw));
            int g = kc * 4 + lq;
#pragma unroll
            for (int ct = 0; ct < 4; ++ct) {
                int c = ct * 16 + lr;
                int addr = c * 128 + ((g ^ lr) << 3);
                half8_t bh = *(const half8_t*)&Whi[addr];
                half8_t bl = *(const half8_t*)&Wlo[addr];
                acc[ct] = __builtin_amdgcn_mfma_f32_16x16x32_f16(a, bh, acc[ct], 0, 0, 0);
                acl[ct] = __builtin_amdgcn_mfma_f32_16x16x32_f16(a, bl, acl[ct], 0, 0, 0);
            }
        }

        int r0 = n0 + lq * 4;
#pragma unroll
        for (int r = 0; r < 4; ++r) {
            int row = r0 + r;
            float d = rsqrtf((float)(row_st[row + 1] - row_st[row] + 1));
#pragma unroll
            for (int ct = 0; ct < 4; ++ct) {
                float v = (acc[ct][r] + acl[ct][r] * 4.8828125e-4f) * d;
                int c = c0 + ct * 16 + lr;
                T[((size_t)(c >> 6) * N_NODES + row) * 64 + (c & 63)] = __float2half(v);
            }
        }
    }
}

// ---------------- layers-2/3 GEMM via MFMA (column-split: 64 cols/block) ----------------
// H read and T written in 2-slice layout: [slice][node][64] fp16 (128-B rows).
__global__ __launch_bounds__(256) void gemm_mfma(const __half* __restrict__ H,
                                                 const float* __restrict__ W,
                                                 const int* __restrict__ row_st,
                                                 __half* __restrict__ T) {
    __shared__ _Float16 Whi[64 * 128];   // 16 KB
    __shared__ _Float16 Wlo[64 * 128];   // 16 KB
    const int t = threadIdx.x;
    const int c0 = (blockIdx.x & 1) * 64;

    for (int i = t; i < 128 * 64; i += 256) {
        int k = i >> 6, c = i & 63;
        float w = W[k * HID + c0 + c];
        _Float16 hi = (_Float16)w;
        _Float16 lo = (_Float16)((w - (float)hi) * 2048.0f);
        int addr = c * 128 + (((k >> 3) ^ (c & 15)) << 3) + (k & 7);
        Whi[addr] = hi;
        Wlo[addr] = lo;
    }
    __syncthreads();

    const int wv = t >> 6;
    const int l  = t & 63;
    const int lr = l & 15;
    const int lq = l >> 4;

    for (int rep = 0; rep < 4; ++rep) {
        int strip = ((blockIdx.x >> 1) * 4 + wv) * 4 + rep;
        if (strip >= N_NODES / 16) continue;
        int n0 = strip * 16;

        f32x4_t acc[4], acl[4];
#pragma unroll
        for (int ct = 0; ct < 4; ++ct) { acc[ct] = (f32x4_t){0,0,0,0}; acl[ct] = (f32x4_t){0,0,0,0}; }

#pragma unroll
        for (int kc = 0; kc < 4; ++kc) {
            // feature f = kc*32 + lq*8 + j -> slice = kc>>1, within-slice = (kc&1)*32 + lq*8
            half8_t a = *(const half8_t*)(H + ((size_t)(kc >> 1) * N_NODES + n0 + lr) * 64
                                            + (kc & 1) * 32 + lq * 8);
#pragma unroll
            for (int j = 0; j < 8; ++j) a[j] = a[j] > (_Float16)0 ? a[j] : (_Float16)0;
            int g = kc * 4 + lq;
#pragma unroll
            for (int ct = 0; ct < 4; ++ct) {
                int c = ct * 16 + lr;
                int addr = c * 128 + ((g ^ lr) << 3);
                half8_t bh = *(const half8_t*)&Whi[addr];
                half8_t bl = *(const half8_t*)&Wlo[addr];
                acc[ct] = __builtin_amdgcn_mfma_f32_16x16x32_f16(a, bh, acc[ct], 0, 0, 0);
                acl[ct] = __builtin_amdgcn_mfma_f32_16x16x32_f16(a, bl, acl[ct], 0, 0, 0);
            }
        }

        int r0 = n0 + lq * 4;
#pragma unroll
        for (int r = 0; r < 4; ++r) {
            int row = r0 + r;
            float d = rsqrtf((float)(row_st[row + 1] - row_st[row] + 1));
#pragma unroll
            for (int ct = 0; ct < 4; ++ct) {
                float v = (acc[ct][r] + acl[ct][r] * 4.8828125e-4f) * d;
                int c = c0 + ct * 16 + lr;
                T[((size_t)(c >> 6) * N_NODES + row) * 64 + (c & 63)] = __float2half(v);
            }
        }
    }
}

// ---------------- XCD-pinned half-gather: 2 slices x 64 features (128-B rows) ----------------
__global__ __launch_bounds__(256) void gather_half(const __half* __restrict__ T,
                                                   const int* __restrict__ row_st,
                                                   const int* __restrict__ csr,
                                                   const float* __restrict__ bias,
                                                   __half* __restrict__ B) {
    int t = threadIdx.x;
    int b = blockIdx.x;
    int x = b & 7;
    int slice = x >> 2;                      // 4 XCDs per 64-feature half
    int chunk = (b >> 3) * 4 + (x & 3);      // dst chunk (32 nodes) within slice
    int n = chunk * 32 + (t >> 3);
    int l = t & 7;                           // uint4 (8 halfs) within 128-B row
    if (n >= N_NODES) return;
    int r0 = row_st[n], r1 = row_st[n + 1];
    float di = rsqrtf((float)(r1 - r0 + 1));
    const uv4* Tf = (const uv4*)T + (size_t)slice * N_NODES * 8;
    uv4 u = Tf[(size_t)n * 8 + l];
    float4 accL = f4_from(u[0], u[1]);       // self term
    float4 accH = f4_from(u[2], u[3]);
    int r = r0;
    for (; r + 7 < r1; r += 8) {
        int s0 = csr[r],     s1 = csr[r + 1], s2 = csr[r + 2], s3 = csr[r + 3];
        int s4 = csr[r + 4], s5 = csr[r + 5], s6 = csr[r + 6], s7 = csr[r + 7];
        uv4 vv0 = Tf[(size_t)s0 * 8 + l];
        uv4 vv1 = Tf[(size_t)s1 * 8 + l];
        uv4 vv2 = Tf[(size_t)s2 * 8 + l];
        uv4 vv3 = Tf[(size_t)s3 * 8 + l];
        uv4 vv4 = Tf[(size_t)s4 * 8 + l];
        uv4 vv5 = Tf[(size_t)s5 * 8 + l];
        uv4 vv6 = Tf[(size_t)s6 * 8 + l];
        uv4 vv7 = Tf[(size_t)s7 * 8 + l];
        uv4 vv[8] = {vv0, vv1, vv2, vv3, vv4, vv5, vv6, vv7};
#pragma unroll
        for (int j = 0; j < 8; ++j) {
            float4 aL = f4_from(vv[j][0], vv[j][1]);
            float4 aH = f4_from(vv[j][2], vv[j][3]);
            accL.x += aL.x; accL.y += aL.y; accL.z += aL.z; accL.w += aL.w;
            accH.x += aH.x; accH.y += aH.y; accH.z += aH.z; accH.w += aH.w;
        }
    }
    for (; r + 3 < r1; r += 4) {
        int s0 = csr[r], s1 = csr[r + 1], s2 = csr[r + 2], s3 = csr[r + 3];
        uv4 vv0 = Tf[(size_t)s0 * 8 + l];
        uv4 vv1 = Tf[(size_t)s1 * 8 + l];
        uv4 vv2 = Tf[(size_t)s2 * 8 + l];
        uv4 vv3 = Tf[(size_t)s3 * 8 + l];
        uv4 vv[4] = {vv0, vv1, vv2, vv3};
#pragma unroll
        for (int j = 0; j < 4; ++j) {
            float4 aL = f4_from(vv[j][0], vv[j][1]);
            float4 aH = f4_from(vv[j][2], vv[j][3]);
            accL.x += aL.x; accL.y += aL.y; accL.z += aL.z; accL.w += aL.w;
            accH.x += aH.x; accH.y += aH.y; accH.z += aH.z; accH.w += aH.w;
        }
    }
    for (; r < r1; ++r) {
        uv4 v = Tf[(size_t)csr[r] * 8 + l];
        float4 aL = f4_from(v[0], v[1]);
        float4 aH = f4_from(v[2], v[3]);
        accL.x += aL.x; accL.y += aL.y; accL.z += aL.z; accL.w += aL.w;
        accH.x += aH.x; accH.y += aH.y; accH.z += aH.z; accH.w += aH.w;
    }
    const float4* bb = (const float4*)bias + slice * 16 + l * 2;
    float4 b0 = bb[0], b1 = bb[1];
    __half2 h0 = __floats2half2_rn(fmaf(di, accL.x, b0.x), fmaf(di, accL.y, b0.y));
    __half2 h1 = __floats2half2_rn(fmaf(di, accL.z, b0.z), fmaf(di, accL.w, b0.w));
    __half2 h2 = __floats2half2_rn(fmaf(di, accH.x, b1.x), fmaf(di, accH.y, b1.y));
    __half2 h3 = __floats2half2_rn(fmaf(di, accH.z, b1.z), fmaf(di, accH.w, b1.w));
    uv4 o;
    o[0] = *(unsigned*)&h0; o[1] = *(unsigned*)&h1;
    o[2] = *(unsigned*)&h2; o[3] = *(unsigned*)&h3;
    uv4* dstp = (uv4*)B + ((size_t)slice * N_NODES + n) * 8 + l;
    __builtin_nontemporal_store(o, dstp);
}

// ---------------- pool + head in one kernel, no atomics (batch is sorted) ----------------
__global__ __launch_bounds__(256) void pool_head(const __half* __restrict__ H,
                                                 const int* __restrict__ batch,
                                                 const float* __restrict__ Wout,
                                                 const float* __restrict__ bout,
                                                 float* __restrict__ out) {
    __shared__ float4 part[8][32];
    __shared__ float p[HID];
    __shared__ int bounds[2];
    int g = blockIdx.x;
    int t = threadIdx.x;
    if (t < 2) {
        int target = g + t;
        int lo = 0, hi = N_NODES;
        while (lo < hi) {
            int mid = (lo + hi) >> 1;
            if (batch[mid] < target) lo = mid + 1; else hi = mid;
        }
        bounds[t] = lo;
    }
    __syncthreads();
    int lo = bounds[0], hi = bounds[1];
    int grp = t >> 5, l = t & 31;
    const uint2* Hf = (const uint2*)H;
    float4 acc = make_float4(0.f, 0.f, 0.f, 0.f);
    // 2-slice read: feature quad l -> slice l>>4, within-slice uint2 idx l&15
    const size_t sbase = (size_t)(l >> 4) * N_NODES;
    const int wi = l & 15;
    for (int n = lo + grp; n < hi; n += 8) {
        float4 v = h4_to_f4(Hf[(sbase + n) * 16 + wi]);
        acc.x += fmaxf(v.x, 0.f);
        acc.y += fmaxf(v.y, 0.f);
        acc.z += fmaxf(v.z, 0.f);
        acc.w += fmaxf(v.w, 0.f);
    }
    part[grp][l] = acc;
    __syncthreads();
    if (t < 32) {
        float4 s = part[0][t];
#pragma unroll
        for (int j = 1; j < 8; ++j) {
            float4 v = part[j][t];
            s.x += v.x; s.y += v.y; s.z += v.z; s.w += v.w;
        }
        float inv = 1.0f / fmaxf((float)(hi - lo), 1.0f);
        p[t * 4 + 0] = s.x * inv;
        p[t * 4 + 1] = s.y * inv;
        p[t * 4 + 2] = s.z * inv;
        p[t * 4 + 3] = s.w * inv;
    }
    __syncthreads();
    if (t < OUT_F) {
        float acc2 = 0.f;
#pragma unroll 8
        for (int k = 0; k < HID; ++k)
            acc2 = fmaf(p[k], Wout[k * OUT_F + t], acc2);
        out[g * OUT_F + t] = acc2 + bout[t];
    }
}

extern "C" void kernel_launch(void* const* d_in, const int* in_sizes, int n_in,
                              void* d_out, int out_size, void* d_ws, size_t ws_size,
                              hipStream_t stream) {
    const float* x     = (const float*)d_in[0];
    const int*   ei    = (const int*)d_in[1];
    const int*   batch = (const int*)d_in[2];
    const float* W1    = (const float*)d_in[3];
    const float* b1    = (const float*)d_in[4];
    const float* W2    = (const float*)d_in[5];
    const float* b2    = (const float*)d_in[6];
    const float* W3    = (const float*)d_in[7];
    const float* b3    = (const float*)d_in[8];
    const float* Wout  = (const float*)d_in[9];
    const float* bout  = (const float*)d_in[10];
    float* out = (float*)d_out;

    const int* src = ei;
    const int* dst = ei + N_EDGES;

    // workspace (within proven footprint)
    float* A      = (float*)d_ws;                        // 12.8M floats (51.2 MB)
    float* Breg   = A + (size_t)N_NODES * HID;           // 12.8M floats (51.2 MB)
    int*   row_st = (int*)(Breg + (size_t)N_NODES * HID);// 100001 ints
    int*   cur512 = row_st + N_NODES + 1;                // 512
    int*   csr    = cur512 + BUCKETS;                    // 1.6M ints

    int*    bpairs = (int*)A;                              // 512*3500*4 = 7.168 MB overlay
    __half* Xs     = (__half*)((char*)A + 7168000);        // 6.4 MB, after bpairs
    __half* T      = (__half*)A;                           // 25.6 MB msg table
    __half* H      = (__half*)Breg;                        // 25.6 MB activation table
    float*  A20    = (float*)((char*)A + 26u * 1024 * 1024); // 12.8 MB, disjoint from T/bpairs/Xs

    // 1. zero bucket cursors + CSR build (coalesced-write versions)
    hipMemsetAsync(cur512, 0, BUCKETS * sizeof(int), stream);
    partition<<<(N_EDGES + EPB - 1) / EPB, 512, 0, stream>>>(src, dst, bpairs, cur512);
    csr_build<<<BUCKETS, 512, 0, stream>>>(bpairs, cur512, row_st, csr, x, Xs);

    // 2. layer 1 gather (barrier-free) -> A20
    gather20<<<(N_NODES + 63) / 64, 256, 0, stream>>>(Xs, row_st, csr, A20);

    // 3. fused layer-1 GEMM + layer-2 weight MFMA: A20 -> T (H never materialized)
    gemm_l1<<<782, 256, 0, stream>>>(A20, W1, b1, W2, row_st, T);

    // 4. layer-2 gather, layer-3 GEMM, layer-3 gather
    gather_half<<<6256, 256, 0, stream>>>(T, row_st, csr, b2, H);
    gemm_mfma<<<782, 256, 0, stream>>>(H, W3, row_st, T);
    gather_half<<<6256, 256, 0, stream>>>(T, row_st, csr, b3, H);

    // 5. pool + head, no atomics
    pool_head<<<N_GRAPHS, 256, 0, stream>>>(H, batch, Wout, bout, out);
}

// Round 10
// 335.088 us; speedup vs baseline: 1.0642x; 1.0642x over previous
//
#include <hip/hip_runtime.h>
#include <hip/hip_fp16.h>

#define N_NODES 100000
#define N_EDGES 1600000
#define N_GRAPHS 512
#define F_IN 20
#define HID 128
#define OUT_F 64

#define BUCKETS 512
#define SPAN 196        // ceil(N_NODES / BUCKETS)
#define BCAP 3500       // per-bucket capacity (mean 3125, +6.7 sigma)
#define EPB 4096        // edges per partition block (512 threads x 8)

typedef _Float16 half8_t __attribute__((ext_vector_type(8)));
typedef float f32x4_t __attribute__((ext_vector_type(4)));
typedef unsigned int uv4 __attribute__((ext_vector_type(4)));

__device__ inline float4 h4_to_f4(uint2 u) {
    __half2 h0 = *(__half2*)&u.x;
    __half2 h1 = *(__half2*)&u.y;
    float2 f0 = __half22float2(h0);
    float2 f1 = __half22float2(h1);
    return make_float4(f0.x, f0.y, f1.x, f1.y);
}

__device__ inline float4 f4_from(unsigned a, unsigned b) {
    __half2 h0 = *(__half2*)&a;
    __half2 h1 = *(__half2*)&b;
    float2 f0 = __half22float2(h0);
    float2 f1 = __half22float2(h1);
    return make_float4(f0.x, f0.y, f1.x, f1.y);
}

__device__ inline void acc8(float4& aL, float4& aH, uv4 v) {
    float4 l_ = f4_from(v[0], v[1]);
    float4 h_ = f4_from(v[2], v[3]);
    aL.x += l_.x; aL.y += l_.y; aL.z += l_.z; aL.w += l_.w;
    aH.x += h_.x; aH.y += h_.y; aH.z += h_.z; aH.w += h_.w;
}

// ---------------- partition: block-sorted LDS staging -> coalesced bucket writes ----------------
__global__ __launch_bounds__(512) void partition(const int* __restrict__ src,
                                                 const int* __restrict__ dst,
                                                 int* __restrict__ bpairs,
                                                 int* cur512) {
    __shared__ int lcnt[8][BUCKETS];          // 16 KB  per-wave counts
    __shared__ int woff[8][BUCKETS];          // 16 KB  per-wave local (block) offsets
    __shared__ int loffx[BUCKETS];            // 2 KB   block exclusive offsets per bucket
    __shared__ int gbase[BUCKETS];            // 2 KB   global reserved base per bucket
    __shared__ int sc[512];                   // 2 KB   scan temp
    __shared__ int stage[EPB];                // 16 KB  staged pairs (bucket-sorted)
    __shared__ unsigned short sbuck[EPB];     // 8 KB   bucket id per staged slot
    __shared__ int stot;
    int t = threadIdx.x;
    int wv = t >> 6;
    for (int i = t; i < 8 * BUCKETS; i += 512) ((int*)lcnt)[i] = 0;
    __syncthreads();
    int base = blockIdx.x * EPB;
    int myb[8], myp[8], myr[8];
#pragma unroll
    for (int i = 0; i < 8; ++i) {
        int e = base + i * 512 + t;
        int b = -1, p = 0, rk = 0;
        if (e < N_EDGES) {
            int s = src[e], d = dst[e];
            b = d / SPAN;
            p = (s << 9) | (d - b * SPAN);
            rk = atomicAdd(&lcnt[wv][b], 1);
        }
        myb[i] = b; myp[i] = p; myr[i] = rk;
    }
    __syncthreads();
    // block totals per bucket + exclusive scan over buckets
    int c[8], tot = 0;
#pragma unroll
    for (int w = 0; w < 8; ++w) { c[w] = lcnt[w][t]; tot += c[w]; }
    sc[t] = tot;
    __syncthreads();
    for (int o = 1; o < BUCKETS; o <<= 1) {
        int v = (t >= o) ? sc[t - o] : 0;
        __syncthreads();
        sc[t] += v;
        __syncthreads();
    }
    int excl = sc[t] - tot;
    loffx[t] = excl;
    gbase[t] = atomicAdd(&cur512[t], tot);    // contiguous global run for this block+bucket
    {
        int lb = excl;
#pragma unroll
        for (int w = 0; w < 8; ++w) { woff[w][t] = lb; lb += c[w]; }
    }
    if (t == 511) stot = sc[511];
    __syncthreads();
    // stage into LDS, bucket-sorted
#pragma unroll
    for (int i = 0; i < 8; ++i) {
        int b = myb[i];
        if (b >= 0) {
            int slot = woff[wv][b] + myr[i];
            stage[slot] = myp[i];
            sbuck[slot] = (unsigned short)b;
        }
    }
    __syncthreads();
    // flush: consecutive staged slots of one bucket -> consecutive global addresses
    int n = stot;
    for (int i = t; i < n; i += 512) {
        int b = sbuck[i];
        int pos = gbase[b] + (i - loffx[b]);
        if (pos < BCAP) bpairs[(size_t)b * BCAP + pos] = stage[i];
    }
}

// ---------------- per-bucket CSR build, 512 thr (LDS-staged csr flush + scale_x) ----------------
__global__ __launch_bounds__(512) void csr_build(const int* __restrict__ bpairs,
                                                 const int* __restrict__ cur512,
                                                 int* __restrict__ row_st,
                                                 int* __restrict__ csr,
                                                 const float* __restrict__ x,
                                                 __half* __restrict__ Xs) {
    __shared__ int ocnt[SPAN];
    __shared__ int sc[512];
    __shared__ int cur[SPAN];
    __shared__ int lcsr[BCAP];    // 14 KB: stage csr segment, flush coalesced
    __shared__ int sbase;
    int b = blockIdx.x, t = threadIdx.x;

    // bucket base: exclusive scan of all 512 bucket counts
    int myc = cur512[t];
    sc[t] = myc;
    __syncthreads();
    for (int o = 1; o < BUCKETS; o <<= 1) {
        int v = (t >= o) ? sc[t - o] : 0;
        __syncthreads();
        sc[t] += v;
        __syncthreads();
    }
    if (t == b) sbase = sc[t] - myc;
    if (b == BUCKETS - 1 && t == 0) row_st[N_NODES] = N_EDGES;

    int n0 = b * SPAN;
    int span = N_NODES - n0; if (span > SPAN) span = SPAN;
    if (span < 0) span = 0;
    if (t < SPAN) ocnt[t] = 0;
    __syncthreads();

    int n = cur512[b];
    if (n > BCAP) n = BCAP;
    const int* p = bpairs + (size_t)b * BCAP;
    for (int i = t; i < n; i += 512) atomicAdd(&ocnt[p[i] & 511], 1);
    __syncthreads();
    sc[t] = (t < span) ? ocnt[t] : 0;
    __syncthreads();
    for (int o = 1; o < 512; o <<= 1) {
        int v = (t >= o) ? sc[t - o] : 0;
        __syncthreads();
        sc[t] += v;
        __syncthreads();
    }
    int base = sbase;
    if (t < span) {
        int start = sc[t] - ocnt[t];
        row_st[n0 + t] = base + start;
        cur[t] = start;
    }
    __syncthreads();
    for (int i = t; i < n; i += 512) {
        int e = p[i];
        int lp = atomicAdd(&cur[e & 511], 1);
        lcsr[lp] = e >> 9;                      // LDS scatter (cheap)
    }
    __syncthreads();
    for (int i = t; i < n; i += 512)            // coalesced global flush
        csr[base + i] = lcsr[i];
    // fused scale_x for this bucket's nodes
    for (int i = t; i < span * 32; i += 512) {
        int nl = i >> 5, f = i & 31;
        float v = (f < F_IN) ? x[(size_t)(n0 + nl) * F_IN + f] : 0.f;
        float di = rsqrtf((float)(ocnt[nl] + 1));
        Xs[(size_t)(n0 + nl) * 32 + f] = __float2half(di * v);
    }
}

// ---------------- layer 1 fused: deep-pipelined gather(F_IN) + GEMM -> H fp16 (2-slice) ----------------
__global__ __launch_bounds__(256) void layer1(const __half* __restrict__ Xs,
                                              const int* __restrict__ row_st,
                                              const int* __restrict__ csr,
                                              const float* __restrict__ W,
                                              const float* __restrict__ bias,
                                              __half* __restrict__ H) {
    __shared__ float Wlds[F_IN * HID];   // 10 KB
    __shared__ float Alds[64][F_IN];     // 5 KB
    const int t = threadIdx.x;
    const int node0 = blockIdx.x * 64;

    for (int i = t; i < F_IN * HID; i += 256) Wlds[i] = W[i];

    const int grp = t >> 2;          // 0..63 -> local node
    const int l   = t & 3;           // uint4 (8 halfs) within 64-B row
    const int n   = node0 + grp;
    if (n < N_NODES) {
        int r0 = row_st[n], r1 = row_st[n + 1];
        const uv4* X4 = (const uv4*)Xs;
        uv4 u = X4[(size_t)n * 4 + l];
        float4 accL = f4_from(u[0], u[1]);   // self term (Xs pre-scaled src-side)
        float4 accH = f4_from(u[2], u[3]);
        int r = r0;
        for (; r + 7 < r1; r += 8) {
            int s0 = csr[r],     s1 = csr[r + 1], s2 = csr[r + 2], s3 = csr[r + 3];
            int s4 = csr[r + 4], s5 = csr[r + 5], s6 = csr[r + 6], s7 = csr[r + 7];
            uv4 vv0 = X4[(size_t)s0 * 4 + l];
            uv4 vv1 = X4[(size_t)s1 * 4 + l];
            uv4 vv2 = X4[(size_t)s2 * 4 + l];
            uv4 vv3 = X4[(size_t)s3 * 4 + l];
            uv4 vv4 = X4[(size_t)s4 * 4 + l];
            uv4 vv5 = X4[(size_t)s5 * 4 + l];
            uv4 vv6 = X4[(size_t)s6 * 4 + l];
            uv4 vv7 = X4[(size_t)s7 * 4 + l];
            uv4 vv[8] = {vv0, vv1, vv2, vv3, vv4, vv5, vv6, vv7};
#pragma unroll
            for (int j = 0; j < 8; ++j) acc8(accL, accH, vv[j]);
        }
        for (; r < r1; ++r) acc8(accL, accH, X4[(size_t)csr[r] * 4 + l]);
        float di = rsqrtf((float)(r1 - r0 + 1));
        // lane l owns features l*8 .. l*8+7; only f < 20 are real
        if (l < 2) {
            int f0 = l * 8;
            Alds[grp][f0 + 0] = di * accL.x;
            Alds[grp][f0 + 1] = di * accL.y;
            Alds[grp][f0 + 2] = di * accL.z;
            Alds[grp][f0 + 3] = di * accL.w;
            Alds[grp][f0 + 4] = di * accH.x;
            Alds[grp][f0 + 5] = di * accH.y;
            Alds[grp][f0 + 6] = di * accH.z;
            Alds[grp][f0 + 7] = di * accH.w;
        } else if (l == 2) {
            Alds[grp][16] = di * accL.x;
            Alds[grp][17] = di * accL.y;
            Alds[grp][18] = di * accL.z;
            Alds[grp][19] = di * accL.w;
        }
    }
    __syncthreads();

    // GEMM phase: thread t -> node (t>>2), cols c(j) = (t&3)*4 + 16*j, j=0..7
    const int nl = t >> 2;
    const int cb = (t & 3) * 4;
    float4 acc[8];
#pragma unroll
    for (int j = 0; j < 8; ++j) acc[j] = *(const float4*)&bias[cb + 16 * j];
#pragma unroll
    for (int k = 0; k < F_IN; ++k) {
        float a = Alds[nl][k];
        const float* Wr = &Wlds[k * HID + cb];
#pragma unroll
        for (int j = 0; j < 8; ++j) {
            float4 w = *(const float4*)&Wr[16 * j];
            acc[j].x = fmaf(a, w.x, acc[j].x);
            acc[j].y = fmaf(a, w.y, acc[j].y);
            acc[j].z = fmaf(a, w.z, acc[j].z);
            acc[j].w = fmaf(a, w.w, acc[j].w);
        }
    }
    if (node0 + nl < N_NODES) {
#pragma unroll
        for (int j = 0; j < 8; ++j) {
            int c = cb + 16 * j;
            int slice = c >> 6;
            int wi = ((c & 63) >> 2);
            __half2 h0 = __floats2half2_rn(acc[j].x, acc[j].y);
            __half2 h1 = __floats2half2_rn(acc[j].z, acc[j].w);
            uint2 u; u.x = *(unsigned*)&h0; u.y = *(unsigned*)&h1;
            ((uint2*)H)[((size_t)slice * N_NODES + node0 + nl) * 16 + wi] = u;
        }
    }
}

// ---------------- layers-2/3 GEMM via MFMA (column-split: 64 cols/block) ----------------
// H read and T written in 2-slice layout: [slice][node][64] fp16 (128-B rows).
__global__ __launch_bounds__(256) void gemm_mfma(const __half* __restrict__ H,
                                                 const float* __restrict__ W,
                                                 const int* __restrict__ row_st,
                                                 __half* __restrict__ T) {
    __shared__ _Float16 Whi[64 * 128];   // 16 KB
    __shared__ _Float16 Wlo[64 * 128];   // 16 KB
    const int t = threadIdx.x;
    const int c0 = (blockIdx.x & 1) * 64;

    for (int i = t; i < 128 * 64; i += 256) {
        int k = i >> 6, c = i & 63;
        float w = W[k * HID + c0 + c];
        _Float16 hi = (_Float16)w;
        _Float16 lo = (_Float16)((w - (float)hi) * 2048.0f);
        int addr = c * 128 + (((k >> 3) ^ (c & 15)) << 3) + (k & 7);
        Whi[addr] = hi;
        Wlo[addr] = lo;
    }
    __syncthreads();

    const int wv = t >> 6;
    const int l  = t & 63;
    const int lr = l & 15;
    const int lq = l >> 4;

    for (int rep = 0; rep < 4; ++rep) {
        int strip = ((blockIdx.x >> 1) * 4 + wv) * 4 + rep;
        if (strip >= N_NODES / 16) continue;
        int n0 = strip * 16;

        f32x4_t acc[4], acl[4];
#pragma unroll
        for (int ct = 0; ct < 4; ++ct) { acc[ct] = (f32x4_t){0,0,0,0}; acl[ct] = (f32x4_t){0,0,0,0}; }

#pragma unroll
        for (int kc = 0; kc < 4; ++kc) {
            // feature f = kc*32 + lq*8 + j -> slice = kc>>1, within-slice = (kc&1)*32 + lq*8
            half8_t a = *(const half8_t*)(H + ((size_t)(kc >> 1) * N_NODES + n0 + lr) * 64
                                            + (kc & 1) * 32 + lq * 8);
#pragma unroll
            for (int j = 0; j < 8; ++j) a[j] = a[j] > (_Float16)0 ? a[j] : (_Float16)0;
            int g = kc * 4 + lq;
#pragma unroll
            for (int ct = 0; ct < 4; ++ct) {
                int c = ct * 16 + lr;
                int addr = c * 128 + ((g ^ lr) << 3);
                half8_t bh = *(const half8_t*)&Whi[addr];
                half8_t bl = *(const half8_t*)&Wlo[addr];
                acc[ct] = __builtin_amdgcn_mfma_f32_16x16x32_f16(a, bh, acc[ct], 0, 0, 0);
                acl[ct] = __builtin_amdgcn_mfma_f32_16x16x32_f16(a, bl, acl[ct], 0, 0, 0);
            }
        }

        int r0 = n0 + lq * 4;
#pragma unroll
        for (int r = 0; r < 4; ++r) {
            int row = r0 + r;
            float d = rsqrtf((float)(row_st[row + 1] - row_st[row] + 1));
#pragma unroll
            for (int ct = 0; ct < 4; ++ct) {
                float v = (acc[ct][r] + acl[ct][r] * 4.8828125e-4f) * d;
                int c = c0 + ct * 16 + lr;
                T[((size_t)(c >> 6) * N_NODES + row) * 64 + (c & 63)] = __float2half(v);
            }
        }
    }
}

// ---------------- XCD-pinned half-gather: 2 slices x 64 features (128-B rows) ----------------
__global__ __launch_bounds__(256) void gather_half(const __half* __restrict__ T,
                                                   const int* __restrict__ row_st,
                                                   const int* __restrict__ csr,
                                                   const float* __restrict__ bias,
                                                   __half* __restrict__ B) {
    int t = threadIdx.x;
    int b = blockIdx.x;
    int x = b & 7;
    int slice = x >> 2;                      // 4 XCDs per 64-feature half
    int chunk = (b >> 3) * 4 + (x & 3);      // dst chunk (32 nodes) within slice
    int n = chunk * 32 + (t >> 3);
    int l = t & 7;                           // uint4 (8 halfs) within 128-B row
    if (n >= N_NODES) return;
    int r0 = row_st[n], r1 = row_st[n + 1];
    float di = rsqrtf((float)(r1 - r0 + 1));
    const uv4* Tf = (const uv4*)T + (size_t)slice * N_NODES * 8;
    uv4 u = Tf[(size_t)n * 8 + l];
    float4 accL = f4_from(u[0], u[1]);       // self term
    float4 accH = f4_from(u[2], u[3]);
    int r = r0;
    for (; r + 7 < r1; r += 8) {
        int s0 = csr[r],     s1 = csr[r + 1], s2 = csr[r + 2], s3 = csr[r + 3];
        int s4 = csr[r + 4], s5 = csr[r + 5], s6 = csr[r + 6], s7 = csr[r + 7];
        uv4 vv0 = Tf[(size_t)s0 * 8 + l];
        uv4 vv1 = Tf[(size_t)s1 * 8 + l];
        uv4 vv2 = Tf[(size_t)s2 * 8 + l];
        uv4 vv3 = Tf[(size_t)s3 * 8 + l];
        uv4 vv4 = Tf[(size_t)s4 * 8 + l];
        uv4 vv5 = Tf[(size_t)s5 * 8 + l];
        uv4 vv6 = Tf[(size_t)s6 * 8 + l];
        uv4 vv7 = Tf[(size_t)s7 * 8 + l];
        uv4 vv[8] = {vv0, vv1, vv2, vv3, vv4, vv5, vv6, vv7};
#pragma unroll
        for (int j = 0; j < 8; ++j) {
            float4 aL = f4_from(vv[j][0], vv[j][1]);
            float4 aH = f4_from(vv[j][2], vv[j][3]);
            accL.x += aL.x; accL.y += aL.y; accL.z += aL.z; accL.w += aL.w;
            accH.x += aH.x; accH.y += aH.y; accH.z += aH.z; accH.w += aH.w;
        }
    }
    for (; r + 3 < r1; r += 4) {
        int s0 = csr[r], s1 = csr[r + 1], s2 = csr[r + 2], s3 = csr[r + 3];
        uv4 vv0 = Tf[(size_t)s0 * 8 + l];
        uv4 vv1 = Tf[(size_t)s1 * 8 + l];
        uv4 vv2 = Tf[(size_t)s2 * 8 + l];
        uv4 vv3 = Tf[(size_t)s3 * 8 + l];
        uv4 vv[4] = {vv0, vv1, vv2, vv3};
#pragma unroll
        for (int j = 0; j < 4; ++j) {
            float4 aL = f4_from(vv[j][0], vv[j][1]);
            float4 aH = f4_from(vv[j][2], vv[j][3]);
            accL.x += aL.x; accL.y += aL.y; accL.z += aL.z; accL.w += aL.w;
            accH.x += aH.x; accH.y += aH.y; accH.z += aH.z; accH.w += aH.w;
        }
    }
    for (; r < r1; ++r) {
        uv4 v = Tf[(size_t)csr[r] * 8 + l];
        float4 aL = f4_from(v[0], v[1]);
        float4 aH = f4_from(v[2], v[3]);
        accL.x += aL.x; accL.y += aL.y; accL.z += aL.z; accL.w += aL.w;
        accH.x += aH.x; accH.y += aH.y; accH.z += aH.z; accH.w += aH.w;
    }
    const float4* bb = (const float4*)bias + slice * 16 + l * 2;
    float4 b0 = bb[0], b1 = bb[1];
    __half2 h0 = __floats2half2_rn(fmaf(di, accL.x, b0.x), fmaf(di, accL.y, b0.y));
    __half2 h1 = __floats2half2_rn(fmaf(di, accL.z, b0.z), fmaf(di, accL.w, b0.w));
    __half2 h2 = __floats2half2_rn(fmaf(di, accH.x, b1.x), fmaf(di, accH.y, b1.y));
    __half2 h3 = __floats2half2_rn(fmaf(di, accH.z, b1.z), fmaf(di, accH.w, b1.w));
    uv4 o;
    o[0] = *(unsigned*)&h0; o[1] = *(unsigned*)&h1;
    o[2] = *(unsigned*)&h2; o[3] = *(unsigned*)&h3;
    uv4* dstp = (uv4*)B + ((size_t)slice * N_NODES + n) * 8 + l;
    __builtin_nontemporal_store(o, dstp);
}

// ---------------- pool + head in one kernel, no atomics (batch is sorted) ----------------
__global__ __launch_bounds__(256) void pool_head(const __half* __restrict__ H,
                                                 const int* __restrict__ batch,
                                                 const float* __restrict__ Wout,
                                                 const float* __restrict__ bout,
                                                 float* __restrict__ out) {
    __shared__ float4 part[8][32];
    __shared__ float p[HID];
    __shared__ int bounds[2];
    int g = blockIdx.x;
    int t = threadIdx.x;
    if (t < 2) {
        int target = g + t;
        int lo = 0, hi = N_NODES;
        while (lo < hi) {
            int mid = (lo + hi) >> 1;
            if (batch[mid] < target) lo = mid + 1; else hi = mid;
        }
        bounds[t] = lo;
    }
    __syncthreads();
    int lo = bounds[0], hi = bounds[1];
    int grp = t >> 5, l = t & 31;
    const uint2* Hf = (const uint2*)H;
    float4 acc = make_float4(0.f, 0.f, 0.f, 0.f);
    // 2-slice read: feature quad l -> slice l>>4, within-slice uint2 idx l&15
    const size_t sbase = (size_t)(l >> 4) * N_NODES;
    const int wi = l & 15;
    for (int n = lo + grp; n < hi; n += 8) {
        float4 v = h4_to_f4(Hf[(sbase + n) * 16 + wi]);
        acc.x += fmaxf(v.x, 0.f);
        acc.y += fmaxf(v.y, 0.f);
        acc.z += fmaxf(v.z, 0.f);
        acc.w += fmaxf(v.w, 0.f);
    }
    part[grp][l] = acc;
    __syncthreads();
    if (t < 32) {
        float4 s = part[0][t];
#pragma unroll
        for (int j = 1; j < 8; ++j) {
            float4 v = part[j][t];
            s.x += v.x; s.y += v.y; s.z += v.z; s.w += v.w;
        }
        float inv = 1.0f / fmaxf((float)(hi - lo), 1.0f);
        p[t * 4 + 0] = s.x * inv;
        p[t * 4 + 1] = s.y * inv;
        p[t * 4 + 2] = s.z * inv;
        p[t * 4 + 3] = s.w * inv;
    }
    __syncthreads();
    if (t < OUT_F) {
        float acc2 = 0.f;
#pragma unroll 8
        for (int k = 0; k < HID; ++k)
            acc2 = fmaf(p[k], Wout[k * OUT_F + t], acc2);
        out[g * OUT_F + t] = acc2 + bout[t];
    }
}

extern "C" void kernel_launch(void* const* d_in, const int* in_sizes, int n_in,
                              void* d_out, int out_size, void* d_ws, size_t ws_size,
                              hipStream_t stream) {
    const float* x     = (const float*)d_in[0];
    const int*   ei    = (const int*)d_in[1];
    const int*   batch = (const int*)d_in[2];
    const float* W1    = (const float*)d_in[3];
    const float* b1    = (const float*)d_in[4];
    const float* W2    = (const float*)d_in[5];
    const float* b2    = (const float*)d_in[6];
    const float* W3    = (const float*)d_in[7];
    const float* b3    = (const float*)d_in[8];
    const float* Wout  = (const float*)d_in[9];
    const float* bout  = (const float*)d_in[10];
    float* out = (float*)d_out;

    const int* src = ei;
    const int* dst = ei + N_EDGES;

    // workspace (within proven footprint)
    float* A      = (float*)d_ws;                        // 12.8M floats
    float* Breg   = A + (size_t)N_NODES * HID;           // 12.8M floats
    int*   row_st = (int*)(Breg + (size_t)N_NODES * HID);// 100001 ints
    int*   cur512 = row_st + N_NODES + 1;                // 512
    int*   csr    = cur512 + BUCKETS;                    // 1.6M ints

    int*    bpairs = (int*)A;                              // 512*3500*4 = 7.168 MB overlay
    __half* Xs     = (__half*)((char*)A + 7168000);        // 6.4 MB, after bpairs
    __half* T      = (__half*)A;                           // 25.6 MB msg table (after layer1)
    __half* H      = (__half*)Breg;                        // 25.6 MB activation table

    // 1. zero bucket cursors + CSR build (coalesced-write versions)
    hipMemsetAsync(cur512, 0, BUCKETS * sizeof(int), stream);
    partition<<<(N_EDGES + EPB - 1) / EPB, 512, 0, stream>>>(src, dst, bpairs, cur512);
    csr_build<<<BUCKETS, 512, 0, stream>>>(bpairs, cur512, row_st, csr, x, Xs);

    // 2. layer 1: deep-pipelined gather(F_IN)+GEMM (2-slice H), 64 nodes/block
    layer1<<<(N_NODES + 63) / 64, 256, 0, stream>>>(Xs, row_st, csr, W1, b1, H);

    // 3. layers 2/3: 2-slice tables, XCD-pinned half-gather (32 nodes/block)
    gemm_mfma<<<782, 256, 0, stream>>>(H, W2, row_st, T);
    gather_half<<<6256, 256, 0, stream>>>(T, row_st, csr, b2, H);
    gemm_mfma<<<782, 256, 0, stream>>>(H, W3, row_st, T);
    gather_half<<<6256, 256, 0, stream>>>(T, row_st, csr, b3, H);

    // 4. pool + head, no atomics
    pool_head<<<N_GRAPHS, 256, 0, stream>>>(H, batch, Wout, bout, out);
}